// Round 15
// baseline (226.810 us; speedup 1.0000x reference)
//
#include <hip/hip_runtime.h>
#include <stdint.h>

#define CIN 128
#define COUT 256
#define NIN 400000
#define MOUT 100000
#define KOFFS 8
#define EPSV 1e-4f
#define BM 64
#define NBLK ((MOUT + BM - 1) / BM)   // 1563
#define THREADS 512

typedef __attribute__((ext_vector_type(8))) short short8;
typedef __attribute__((ext_vector_type(4))) float f32x4;

__device__ __forceinline__ unsigned f2bf_u(float f) {
  union { float f; unsigned u; } v; v.f = f;
  return (v.u + 0x7FFFu + ((v.u >> 16) & 1u)) >> 16;  // RNE bf16
}

// ---------------------------------------------------------------------------
// Kernel 0: W[k][c][n] fp32 -> Wt in MFMA-fragment order (R14 layout):
//   Wt[s][wn32][g][lane][e], wn32 = 32-col group, g = ks*2 + half16.
// ---------------------------------------------------------------------------
__global__ void prep_kernel(const float* __restrict__ W,
                            unsigned short* __restrict__ Wt) {
  __shared__ unsigned short t[64][257];
  const int s = blockIdx.x;
  const int tid = threadIdx.x;  // 256
  const int koff = s >> 1;
  const int cbase = (s & 1) * 64;
  const float* Wk = W + koff * (CIN * COUT);
  #pragma unroll 8
  for (int c = 0; c < 64; ++c)
    t[c][tid] = (unsigned short)f2bf_u(Wk[(cbase + c) * COUT + tid]);
  __syncthreads();
  uint4* dst = (uint4*)((char*)Wt + s * 32768);
  #pragma unroll
  for (int p = 0; p < 8; ++p) {
    int f = p * 256 + tid;
    int wn = f >> 8, rem = f & 255;
    int g = rem >> 6, l = rem & 63;
    int ks = g >> 1, ni = g & 1;
    int n = wn * 32 + ni * 16 + (l & 15);
    int cb = ks * 32 + ((l >> 4) << 3);
    uint4 w;
    w.x = (unsigned)t[cb + 0][n] | ((unsigned)t[cb + 1][n] << 16);
    w.y = (unsigned)t[cb + 2][n] | ((unsigned)t[cb + 3][n] << 16);
    w.z = (unsigned)t[cb + 4][n] | ((unsigned)t[cb + 5][n] << 16);
    w.w = (unsigned)t[cb + 6][n] | ((unsigned)t[cb + 7][n] << 16);
    dst[f] = w;
  }
}

// ---------------------------------------------------------------------------
// Kernel 1: conv. M-SPLIT waves: 8 waves = 4 wm x 2 wn; wave tile 16r x 128c.
// Per half-step: 1 A-frag LDS read (4x fewer than R14), 8 B-frags (1KB
// contiguous, P/Q prefetch). uint4 stage writes (bank-free), IDX stride 9.
// ---------------------------------------------------------------------------
__global__ __launch_bounds__(THREADS, 2) void conv_kernel(
    const float* __restrict__ feats,
    const unsigned short* __restrict__ Wt,
    const int* __restrict__ gidx,
    unsigned short* __restrict__ rawout,
    float* __restrict__ out32,
    float* __restrict__ partial) {
  __shared__ unsigned short Asm[257 * 128];   // 257 rows x 256 B (row 256 = 0)
  __shared__ int IDXs[64 * 9 + 8];            // stride-9 pad: conflict-free

  const int tid = threadIdx.x;
  const int lane = tid & 63;
  const int wave = tid >> 6;
  const int wm = wave >> 1;        // 0..3: 16-row group
  const int wn = wave & 1;         // 0..1: 128-col half
  const int row16 = lane & 15;
  const int quad = lane >> 4;
  const long base_m = (long)blockIdx.x * BM;
  const long in_base = 4 * base_m;

  {
    int r = tid >> 3, k = tid & 7;
    long m = base_m + r;
    int idx = (m < MOUT) ? gidx[m * KOFFS + k] : NIN;
    long li = (long)idx - in_base;
    IDXs[r * 9 + k] = ((unsigned long)li > 255ul) ? 256 : (int)li;
  }
  if (tid < 16) *(uint4*)((char*)Asm + 256 * 256 + tid * 16) = make_uint4(0, 0, 0, 0);

  // ---- linear A stage: 8 x (32B load -> uint4 LDS write) per thread ----
  {
    const float4* f4 = (const float4*)feats + in_base * 32;
    const bool full = (in_base + 256 <= NIN);
    #pragma unroll
    for (int p = 0; p < 8; ++p) {
      int g = p * THREADS + tid;         // 16B-granule index 0..4095
      int row = g >> 4, slot = g & 15;
      float4 a, b;
      if (full || in_base + row < NIN) { a = f4[2 * g]; b = f4[2 * g + 1]; }
      else { a = make_float4(0.f,0.f,0.f,0.f); b = a; }
      uint4 w;
      w.x = f2bf_u(a.x) | (f2bf_u(a.y) << 16);
      w.y = f2bf_u(a.z) | (f2bf_u(a.w) << 16);
      w.z = f2bf_u(b.x) | (f2bf_u(b.y) << 16);
      w.w = f2bf_u(b.z) | (f2bf_u(b.w) << 16);
      *(uint4*)((char*)Asm + row * 256 + (((slot) ^ (row & 7)) << 4)) = w;
    }
  }
  __syncthreads();

  const char* Wtc = (const char*)Wt;
  // B frag address: step s, ks, ni(0..7): col = wn*128 + ni*16
  auto BLD = [&](int s, int ks, int ni) -> short8 {
    return *(const short8*)(Wtc + s * 32768 + (wn * 4 + (ni >> 1)) * 4096 +
                            (ks * 2 + (ni & 1)) * 1024 + (lane << 4));
  };
  // A frag: lane&15 = m-row, quad = k-quad
  auto AF = [&](int li, int s, int ks) -> short8 {
    int inner = ((s & 1) << 7) + (ks << 6) + (quad << 4);
    return *(const short8*)((const char*)Asm + li * 256 +
                            (inner ^ ((li & 7) << 4)));
  };

  f32x4 acc[8];
  #pragma unroll
  for (int ni = 0; ni < 8; ++ni) acc[ni] = (f32x4){0.f, 0.f, 0.f, 0.f};

  short8 P[8], Q[8];
  const int myrow9 = (wm * 16 + row16) * 9;

  // prologue: P = (step 0, ks 0)
  #pragma unroll
  for (int ni = 0; ni < 8; ++ni) P[ni] = BLD(0, 0, ni);

  #pragma unroll
  for (int s = 0; s < 16; ++s) {
    const int li = IDXs[myrow9 + (s >> 1)];
    #pragma unroll
    for (int ni = 0; ni < 8; ++ni) Q[ni] = BLD(s, 1, ni);   // prefetch ks1
    {
      short8 a = AF(li, s, 0);
      __builtin_amdgcn_s_setprio(1);
      #pragma unroll
      for (int ni = 0; ni < 8; ++ni)
        acc[ni] = __builtin_amdgcn_mfma_f32_16x16x32_bf16(a, P[ni], acc[ni], 0, 0, 0);
      __builtin_amdgcn_s_setprio(0);
    }
    if (s + 1 < 16) {
      #pragma unroll
      for (int ni = 0; ni < 8; ++ni) P[ni] = BLD(s + 1, 0, ni);  // prefetch next
    }
    {
      short8 a = AF(li, s, 1);
      __builtin_amdgcn_s_setprio(1);
      #pragma unroll
      for (int ni = 0; ni < 8; ++ni)
        acc[ni] = __builtin_amdgcn_mfma_f32_16x16x32_bf16(a, Q[ni], acc[ni], 0, 0, 0);
      __builtin_amdgcn_s_setprio(0);
    }
  }

  // ---- epilogue: raw store + stats ----
  float sm[8], sq[8];
  #pragma unroll
  for (int ni = 0; ni < 8; ++ni) { sm[ni] = 0.f; sq[ni] = 0.f; }
  #pragma unroll
  for (int ni = 0; ni < 8; ++ni) {
    #pragma unroll
    for (int rr = 0; rr < 4; ++rr) {
      long m = base_m + wm * 16 + (quad << 2) + rr;
      float v = acc[ni][rr];
      int n = wn * 128 + (ni << 4) + row16;
      if (m < MOUT) {
        if (rawout) rawout[m * COUT + n] = (unsigned short)f2bf_u(v);
        else        out32[m * COUT + n] = v;
      }
      sm[ni] += v;      // tail rows are exact zeros
      sq[ni] += v * v;
    }
  }
  #pragma unroll
  for (int ni = 0; ni < 8; ++ni) {
    sm[ni] += __shfl_xor(sm[ni], 16);
    sm[ni] += __shfl_xor(sm[ni], 32);
    sq[ni] += __shfl_xor(sq[ni], 16);
    sq[ni] += __shfl_xor(sq[ni], 32);
  }
  __syncthreads();                      // Asm reads done; reuse as scratch
  float* S = (float*)Asm;               // [4][256] sums, then [4][256] sq
  float* Sq = S + 1024;
  if (quad == 0) {
    #pragma unroll
    for (int ni = 0; ni < 8; ++ni) {
      int n = wn * 128 + (ni << 4) + row16;
      S[wm * 256 + n] = sm[ni];
      Sq[wm * 256 + n] = sq[ni];
    }
  }
  __syncthreads();
  if (tid < 256) {
    float s = S[tid] + S[256 + tid] + S[512 + tid] + S[768 + tid];
    partial[(long)blockIdx.x * 512 + tid] = s;
  } else {
    int n = tid - 256;
    float q = Sq[n] + Sq[256 + n] + Sq[512 + n] + Sq[768 + n];
    partial[(long)blockIdx.x * 512 + tid] = q;
  }
}

// ---------------------------------------------------------------------------
// Kernel 2: reduce partial[1563][512] -> partial2[64][512]
// ---------------------------------------------------------------------------
__global__ void reduce_kernel(const float* __restrict__ partial,
                              float* __restrict__ partial2) {
  const int j = blockIdx.x;       // 0..63
  const int c = threadIdx.x;      // 0..511
  const int b0 = j * 25;
  const int b1 = (b0 + 25 < NBLK) ? b0 + 25 : NBLK;
  float s = 0.f;
  for (int b = b0; b < b1; ++b) s += partial[(long)b * 512 + c];
  partial2[(long)j * 512 + c] = s;
}

// ---------------------------------------------------------------------------
// Kernel 3: partial2 -> scale/shift
// ---------------------------------------------------------------------------
__global__ void finalize_kernel(const float* __restrict__ partial2,
                                const float* __restrict__ gamma,
                                const float* __restrict__ beta,
                                float* __restrict__ ss) {
  int n = threadIdx.x;            // 0..255
  float s = 0.f, q = 0.f;
  #pragma unroll
  for (int j = 0; j < 64; ++j) {
    s += partial2[j * 512 + n];
    q += partial2[j * 512 + 256 + n];
  }
  const float inv = 1.0f / (float)MOUT;
  float mu = s * inv;
  float var = q * inv - mu * mu;
  float sc = rsqrtf(var + EPSV) * gamma[n];
  ss[n] = sc;
  ss[n + 256] = beta[n] - mu * sc;
}

// ---------------------------------------------------------------------------
// Kernel 4a: BN + ReLU from bf16 raw -> f32 out
// ---------------------------------------------------------------------------
__global__ void apply_bf16(const unsigned short* __restrict__ raw,
                           float* __restrict__ out,
                           const float* __restrict__ ss) {
  const int c0 = (threadIdx.x & 31) << 3;
  float scr[8], shr[8];
  #pragma unroll
  for (int j = 0; j < 8; ++j) { scr[j] = ss[c0 + j]; shr[j] = ss[c0 + j + 256]; }
  const long total = (long)MOUT * COUT / 8;
  const uint4* r4 = (const uint4*)raw;
  float4* o4 = (float4*)out;
  union { unsigned u; float f; } t;
  for (long i = (long)blockIdx.x * blockDim.x + threadIdx.x; i < total;
       i += (long)gridDim.x * blockDim.x) {
    uint4 v = r4[i];
    float4 a, b;
    t.u = v.x << 16;        a.x = t.f;
    t.u = v.x & 0xffff0000; a.y = t.f;
    t.u = v.y << 16;        a.z = t.f;
    t.u = v.y & 0xffff0000; a.w = t.f;
    t.u = v.z << 16;        b.x = t.f;
    t.u = v.z & 0xffff0000; b.y = t.f;
    t.u = v.w << 16;        b.z = t.f;
    t.u = v.w & 0xffff0000; b.w = t.f;
    a.x = fmaxf(fmaf(a.x, scr[0], shr[0]), 0.f);
    a.y = fmaxf(fmaf(a.y, scr[1], shr[1]), 0.f);
    a.z = fmaxf(fmaf(a.z, scr[2], shr[2]), 0.f);
    a.w = fmaxf(fmaf(a.w, scr[3], shr[3]), 0.f);
    b.x = fmaxf(fmaf(b.x, scr[4], shr[4]), 0.f);
    b.y = fmaxf(fmaf(b.y, scr[5], shr[5]), 0.f);
    b.z = fmaxf(fmaf(b.z, scr[6], shr[6]), 0.f);
    b.w = fmaxf(fmaf(b.w, scr[7], shr[7]), 0.f);
    o4[2 * i] = a;
    o4[2 * i + 1] = b;
  }
}

// ---------------------------------------------------------------------------
// Kernel 4b: in-place BN + ReLU on f32 out (fallback)
// ---------------------------------------------------------------------------
__global__ void apply_f32(float* __restrict__ out, const float* __restrict__ ss) {
  __shared__ float sc[256], sh[256];
  sc[threadIdx.x] = ss[threadIdx.x];
  sh[threadIdx.x] = ss[threadIdx.x + 256];
  __syncthreads();
  const long total = (long)MOUT * COUT / 4;
  float4* o4 = (float4*)out;
  for (long i = (long)blockIdx.x * blockDim.x + threadIdx.x; i < total;
       i += (long)gridDim.x * blockDim.x) {
    float4 v = o4[i];
    int c = (int)(i & 63) << 2;
    v.x = fmaxf(fmaf(v.x, sc[c],     sh[c]),     0.f);
    v.y = fmaxf(fmaf(v.y, sc[c + 1], sh[c + 1]), 0.f);
    v.z = fmaxf(fmaf(v.z, sc[c + 2], sh[c + 2]), 0.f);
    v.w = fmaxf(fmaf(v.w, sc[c + 3], sh[c + 3]), 0.f);
    o4[i] = v;
  }
}

// ---------------------------------------------------------------------------
extern "C" void kernel_launch(void* const* d_in, const int* in_sizes, int n_in,
                              void* d_out, int out_size, void* d_ws, size_t ws_size,
                              hipStream_t stream) {
  const float* feats = (const float*)d_in[0];
  const float* W     = (const float*)d_in[1];
  const float* gamma = (const float*)d_in[2];
  const float* beta  = (const float*)d_in[3];
  const int*   gidx  = (const int*)d_in[4];
  float* out = (float*)d_out;

  float* ss = (float*)d_ws;                                     // 2 KB
  unsigned short* Wt = (unsigned short*)((char*)d_ws + 4096);   // 512 KB
  float* partial  = (float*)((char*)d_ws + 4096 + 524288);      // 3.2 MB
  float* partial2 = (float*)((char*)partial + (size_t)NBLK * 512 * 4);  // 128 KB
  size_t raw_off = 4096 + 524288 + (size_t)NBLK * 512 * 4 + 131072;
  raw_off = (raw_off + 255) & ~(size_t)255;
  const size_t RAW_BYTES = (size_t)MOUT * COUT * 2;
  bool bf16raw = ws_size >= raw_off + RAW_BYTES;
  unsigned short* raw = bf16raw ? (unsigned short*)((char*)d_ws + raw_off) : nullptr;

  hipLaunchKernelGGL(prep_kernel, dim3(16), dim3(256), 0, stream, W, Wt);
  hipLaunchKernelGGL(conv_kernel, dim3(NBLK), dim3(THREADS), 0, stream,
                     feats, Wt, gidx, raw, bf16raw ? nullptr : out, partial);
  hipLaunchKernelGGL(reduce_kernel, dim3(64), dim3(512), 0, stream,
                     partial, partial2);
  hipLaunchKernelGGL(finalize_kernel, dim3(1), dim3(256), 0, stream,
                     partial2, gamma, beta, ss);
  if (bf16raw)
    hipLaunchKernelGGL(apply_bf16, dim3(2048), dim3(256), 0, stream, raw, out, ss);
  else
    hipLaunchKernelGGL(apply_f32, dim3(2048), dim3(256), 0, stream, out, ss);
}

// Round 16
// 136.731 us; speedup vs baseline: 1.6588x; 1.6588x over previous
//
#include <hip/hip_runtime.h>
#include <hip/hip_bf16.h>
#include <stdint.h>

#define CIN 128
#define COUT 256
#define NIN 400000
#define MOUT 100000
#define KOFFS 8
#define EPSV 1e-4f
#define BM 64
#define NBLK ((MOUT + BM - 1) / BM)   // 1563
#define THREADS 512

typedef __attribute__((ext_vector_type(8))) short short8;
typedef __attribute__((ext_vector_type(4))) float f32x4;

__device__ __forceinline__ unsigned f2bf_u(float f) {
  union { float f; unsigned u; } v; v.f = f;
  return (v.u + 0x7FFFu + ((v.u >> 16) & 1u)) >> 16;  // RNE bf16
}

__device__ __forceinline__ unsigned pk2bf(float a, float b) {
  __hip_bfloat162 p = __float22bfloat162_rn(make_float2(a, b));
  union { __hip_bfloat162 h; unsigned u; } c; c.h = p;
  return c.u;                          // v_cvt_pk_bf16_f32 (RNE), 1 instr
}

// ---------------------------------------------------------------------------
// Kernel 0: W[k][c][n] fp32 -> Wt in MFMA-fragment order (R14 layout):
//   Wt[s][wn][g][lane][e]  -> conv's per-wave frag read = 1KB contiguous.
// ---------------------------------------------------------------------------
__global__ void prep_kernel(const float* __restrict__ W,
                            unsigned short* __restrict__ Wt) {
  __shared__ unsigned short t[64][257];
  const int s = blockIdx.x;
  const int tid = threadIdx.x;  // 256
  const int koff = s >> 1;
  const int cbase = (s & 1) * 64;
  const float* Wk = W + koff * (CIN * COUT);
  #pragma unroll 8
  for (int c = 0; c < 64; ++c)
    t[c][tid] = (unsigned short)f2bf_u(Wk[(cbase + c) * COUT + tid]);
  __syncthreads();
  uint4* dst = (uint4*)((char*)Wt + s * 32768);
  #pragma unroll
  for (int p = 0; p < 8; ++p) {
    int f = p * 256 + tid;
    int wn = f >> 8, rem = f & 255;
    int g = rem >> 6, l = rem & 63;
    int ks = g >> 1, ni = g & 1;
    int n = wn * 32 + ni * 16 + (l & 15);
    int cb = ks * 32 + ((l >> 4) << 3);
    uint4 w;
    w.x = (unsigned)t[cb + 0][n] | ((unsigned)t[cb + 1][n] << 16);
    w.y = (unsigned)t[cb + 2][n] | ((unsigned)t[cb + 3][n] << 16);
    w.z = (unsigned)t[cb + 4][n] | ((unsigned)t[cb + 5][n] << 16);
    w.w = (unsigned)t[cb + 6][n] | ((unsigned)t[cb + 7][n] << 16);
    dst[f] = w;
  }
}

// ---------------------------------------------------------------------------
// Kernel 1: gather-GEMM conv — R14 structure + cvt_pk staging + hoisted
// B prefetch. Linear A stage, LDS indirection, barrier-free K-loop.
// ---------------------------------------------------------------------------
__global__ __launch_bounds__(THREADS, 2) void conv_kernel(
    const float* __restrict__ feats,
    const unsigned short* __restrict__ Wt,
    const int* __restrict__ gidx,
    unsigned short* __restrict__ rawout,
    float* __restrict__ out32,
    float* __restrict__ partial) {
  __shared__ unsigned short Asm[257 * 128];   // 257 rows x 256 B (row 256 = 0)
  __shared__ int IDXs[BM * KOFFS];

  const int tid = threadIdx.x;
  const int lane = tid & 63;
  const int wave = tid >> 6;       // col-group 0..7 (32 cols each)
  const int row16 = lane & 15;
  const int quad = lane >> 4;
  const long base_m = (long)blockIdx.x * BM;
  const long in_base = 4 * base_m;

  // ---- B frags for step 0: issue FIRST (L2 latency hides under staging) ----
  short8 B0a, B0b, B1a, B1b;
  auto B_LOAD0 = [&](int s) {
    const char* bp = (const char*)Wt + s * 32768 + (wave << 12) + (lane << 4);
    B0a = *(const short8*)(bp);            // g0: ks=0, ni=0
    B0b = *(const short8*)(bp + 1024);     // g1: ks=0, ni=1
  };
  auto B_LOAD1 = [&](int s) {
    const char* bp = (const char*)Wt + s * 32768 + (wave << 12) + 2048 + (lane << 4);
    B1a = *(const short8*)(bp);            // g2: ks=1, ni=0
    B1b = *(const short8*)(bp + 1024);     // g3: ks=1, ni=1
  };
  B_LOAD0(0);

  for (int i = tid; i < BM * KOFFS; i += THREADS) {
    long m = base_m + (i >> 3);
    int idx = (m < MOUT) ? gidx[m * KOFFS + (i & 7)] : NIN;
    long li = (long)idx - in_base;
    IDXs[i] = ((unsigned long)li > 255ul) ? 256 : (int)li;
  }
  if (tid < 16) *(uint4*)((char*)Asm + 256 * 256 + tid * 16) = make_uint4(0, 0, 0, 0);

  // ---- linear A stage: 16 float4/thread, cvt_pk conversion ----
  {
    const float4* f4 = (const float4*)feats + in_base * 32;
    float4 v[16];
    if (in_base + 256 <= NIN) {
      #pragma unroll
      for (int p = 0; p < 16; ++p) v[p] = f4[p * THREADS + tid];
    } else {
      #pragma unroll
      for (int p = 0; p < 16; ++p) {
        int j = p * THREADS + tid;
        v[p] = (in_base + (j >> 5) < NIN) ? f4[j]
                                          : make_float4(0.f, 0.f, 0.f, 0.f);
      }
    }
    #pragma unroll
    for (int p = 0; p < 16; ++p) {
      int j = p * THREADS + tid;
      int row = j >> 5, ch4 = j & 31;
      uint2 w;
      w.x = pk2bf(v[p].x, v[p].y);
      w.y = pk2bf(v[p].z, v[p].w);
      *(uint2*)((char*)Asm + row * 256 + ((ch4 * 8) ^ ((row & 7) << 4))) = w;
    }
  }
  __syncthreads();

  f32x4 acc[4][2];
  #pragma unroll
  for (int mi = 0; mi < 4; ++mi)
    #pragma unroll
    for (int ni = 0; ni < 2; ++ni)
      acc[mi][ni] = (f32x4){0.f, 0.f, 0.f, 0.f};

  int li0, li1, li2, li3;
  auto LI_LOAD = [&](int k) {
    li0 = IDXs[(row16) * 8 + k];
    li1 = IDXs[(row16 + 16) * 8 + k];
    li2 = IDXs[(row16 + 32) * 8 + k];
    li3 = IDXs[(row16 + 48) * 8 + k];
  };
  auto AF = [&](int li, int inner) -> short8 {
    return *(const short8*)((const char*)Asm + li * 256 +
                            (inner ^ ((li & 7) << 4)));
  };

  auto MMA0 = [&](int half) {
    const int inner = (half << 7) + (quad << 4);
    short8 a0 = AF(li0, inner), a1 = AF(li1, inner),
           a2 = AF(li2, inner), a3 = AF(li3, inner);
    __builtin_amdgcn_s_setprio(1);
    acc[0][0] = __builtin_amdgcn_mfma_f32_16x16x32_bf16(a0, B0a, acc[0][0], 0, 0, 0);
    acc[0][1] = __builtin_amdgcn_mfma_f32_16x16x32_bf16(a0, B0b, acc[0][1], 0, 0, 0);
    acc[1][0] = __builtin_amdgcn_mfma_f32_16x16x32_bf16(a1, B0a, acc[1][0], 0, 0, 0);
    acc[1][1] = __builtin_amdgcn_mfma_f32_16x16x32_bf16(a1, B0b, acc[1][1], 0, 0, 0);
    acc[2][0] = __builtin_amdgcn_mfma_f32_16x16x32_bf16(a2, B0a, acc[2][0], 0, 0, 0);
    acc[2][1] = __builtin_amdgcn_mfma_f32_16x16x32_bf16(a2, B0b, acc[2][1], 0, 0, 0);
    acc[3][0] = __builtin_amdgcn_mfma_f32_16x16x32_bf16(a3, B0a, acc[3][0], 0, 0, 0);
    acc[3][1] = __builtin_amdgcn_mfma_f32_16x16x32_bf16(a3, B0b, acc[3][1], 0, 0, 0);
    __builtin_amdgcn_s_setprio(0);
  };
  auto MMA1 = [&](int half) {
    const int inner = (half << 7) + 64 + (quad << 4);
    short8 a0 = AF(li0, inner), a1 = AF(li1, inner),
           a2 = AF(li2, inner), a3 = AF(li3, inner);
    __builtin_amdgcn_s_setprio(1);
    acc[0][0] = __builtin_amdgcn_mfma_f32_16x16x32_bf16(a0, B1a, acc[0][0], 0, 0, 0);
    acc[0][1] = __builtin_amdgcn_mfma_f32_16x16x32_bf16(a0, B1b, acc[0][1], 0, 0, 0);
    acc[1][0] = __builtin_amdgcn_mfma_f32_16x16x32_bf16(a1, B1a, acc[1][0], 0, 0, 0);
    acc[1][1] = __builtin_amdgcn_mfma_f32_16x16x32_bf16(a1, B1b, acc[1][1], 0, 0, 0);
    acc[2][0] = __builtin_amdgcn_mfma_f32_16x16x32_bf16(a2, B1a, acc[2][0], 0, 0, 0);
    acc[2][1] = __builtin_amdgcn_mfma_f32_16x16x32_bf16(a2, B1b, acc[2][1], 0, 0, 0);
    acc[3][0] = __builtin_amdgcn_mfma_f32_16x16x32_bf16(a3, B1a, acc[3][0], 0, 0, 0);
    acc[3][1] = __builtin_amdgcn_mfma_f32_16x16x32_bf16(a3, B1b, acc[3][1], 0, 0, 0);
    __builtin_amdgcn_s_setprio(0);
  };

  // ---- 16 macro-steps, barrier-free ----
  #pragma unroll
  for (int T = 0; T < 16; ++T) {
    const int k = T >> 1, half = T & 1;
    if (half == 0) LI_LOAD(k);
    B_LOAD1(T);
    MMA0(half);
    if (T + 1 < 16) B_LOAD0(T + 1);
    MMA1(half);
  }

  // ---- epilogue: raw store + per-channel sums (plain stores) ----
  float sm[2], sq[2];
  sm[0] = sm[1] = sq[0] = sq[1] = 0.f;
  #pragma unroll
  for (int mi = 0; mi < 4; ++mi) {
    #pragma unroll
    for (int rr = 0; rr < 4; ++rr) {
      long m = base_m + (mi << 4) + (quad << 2) + rr;
      bool ok = (m < MOUT);
      #pragma unroll
      for (int ni = 0; ni < 2; ++ni) {
        float v = acc[mi][ni][rr];
        int n = (wave << 5) + (ni << 4) + row16;
        if (ok) {
          if (rawout) rawout[m * COUT + n] = (unsigned short)f2bf_u(v);
          else        out32[m * COUT + n] = v;
        }
        sm[ni] += v;
        sq[ni] += v * v;
      }
    }
  }
  #pragma unroll
  for (int ni = 0; ni < 2; ++ni) {
    sm[ni] += __shfl_xor(sm[ni], 16);
    sm[ni] += __shfl_xor(sm[ni], 32);
    sq[ni] += __shfl_xor(sq[ni], 16);
    sq[ni] += __shfl_xor(sq[ni], 32);
  }
  if (quad == 0) {
    float* pb = partial + (long)blockIdx.x * 512;
    #pragma unroll
    for (int ni = 0; ni < 2; ++ni) {
      int n = (wave << 5) + (ni << 4) + row16;
      pb[n] = sm[ni];
      pb[n + 256] = sq[ni];
    }
  }
}

// ---------------------------------------------------------------------------
// Kernel 2: reduce partial[1563][512] -> partial2[64][512]
// ---------------------------------------------------------------------------
__global__ void reduce_kernel(const float* __restrict__ partial,
                              float* __restrict__ partial2) {
  const int j = blockIdx.x;       // 0..63
  const int c = threadIdx.x;      // 0..511
  const int b0 = j * 25;
  const int b1 = (b0 + 25 < NBLK) ? b0 + 25 : NBLK;
  float s = 0.f;
  for (int b = b0; b < b1; ++b) s += partial[(long)b * 512 + c];
  partial2[(long)j * 512 + c] = s;
}

// ---------------------------------------------------------------------------
// Kernel 3: partial2 -> scale/shift
// ---------------------------------------------------------------------------
__global__ void finalize_kernel(const float* __restrict__ partial2,
                                const float* __restrict__ gamma,
                                const float* __restrict__ beta,
                                float* __restrict__ ss) {
  int n = threadIdx.x;            // 0..255
  float s = 0.f, q = 0.f;
  #pragma unroll
  for (int j = 0; j < 64; ++j) {
    s += partial2[j * 512 + n];
    q += partial2[j * 512 + 256 + n];
  }
  const float inv = 1.0f / (float)MOUT;
  float mu = s * inv;
  float var = q * inv - mu * mu;
  float sc = rsqrtf(var + EPSV) * gamma[n];
  ss[n] = sc;
  ss[n + 256] = beta[n] - mu * sc;
}

// ---------------------------------------------------------------------------
// Kernel 4a: BN + ReLU from bf16 raw -> f32 out
// ---------------------------------------------------------------------------
__global__ void apply_bf16(const unsigned short* __restrict__ raw,
                           float* __restrict__ out,
                           const float* __restrict__ ss) {
  const int c0 = (threadIdx.x & 31) << 3;
  float scr[8], shr[8];
  #pragma unroll
  for (int j = 0; j < 8; ++j) { scr[j] = ss[c0 + j]; shr[j] = ss[c0 + j + 256]; }
  const long total = (long)MOUT * COUT / 8;
  const uint4* r4 = (const uint4*)raw;
  float4* o4 = (float4*)out;
  union { unsigned u; float f; } t;
  for (long i = (long)blockIdx.x * blockDim.x + threadIdx.x; i < total;
       i += (long)gridDim.x * blockDim.x) {
    uint4 v = r4[i];
    float4 a, b;
    t.u = v.x << 16;        a.x = t.f;
    t.u = v.x & 0xffff0000; a.y = t.f;
    t.u = v.y << 16;        a.z = t.f;
    t.u = v.y & 0xffff0000; a.w = t.f;
    t.u = v.z << 16;        b.x = t.f;
    t.u = v.z & 0xffff0000; b.y = t.f;
    t.u = v.w << 16;        b.z = t.f;
    t.u = v.w & 0xffff0000; b.w = t.f;
    a.x = fmaxf(fmaf(a.x, scr[0], shr[0]), 0.f);
    a.y = fmaxf(fmaf(a.y, scr[1], shr[1]), 0.f);
    a.z = fmaxf(fmaf(a.z, scr[2], shr[2]), 0.f);
    a.w = fmaxf(fmaf(a.w, scr[3], shr[3]), 0.f);
    b.x = fmaxf(fmaf(b.x, scr[4], shr[4]), 0.f);
    b.y = fmaxf(fmaf(b.y, scr[5], shr[5]), 0.f);
    b.z = fmaxf(fmaf(b.z, scr[6], shr[6]), 0.f);
    b.w = fmaxf(fmaf(b.w, scr[7], shr[7]), 0.f);
    o4[2 * i] = a;
    o4[2 * i + 1] = b;
  }
}

// ---------------------------------------------------------------------------
// Kernel 4b: in-place BN + ReLU on f32 out (fallback)
// ---------------------------------------------------------------------------
__global__ void apply_f32(float* __restrict__ out, const float* __restrict__ ss) {
  __shared__ float sc[256], sh[256];
  sc[threadIdx.x] = ss[threadIdx.x];
  sh[threadIdx.x] = ss[threadIdx.x + 256];
  __syncthreads();
  const long total = (long)MOUT * COUT / 4;
  float4* o4 = (float4*)out;
  for (long i = (long)blockIdx.x * blockDim.x + threadIdx.x; i < total;
       i += (long)gridDim.x * blockDim.x) {
    float4 v = o4[i];
    int c = (int)(i & 63) << 2;
    v.x = fmaxf(fmaf(v.x, sc[c],     sh[c]),     0.f);
    v.y = fmaxf(fmaf(v.y, sc[c + 1], sh[c + 1]), 0.f);
    v.z = fmaxf(fmaf(v.z, sc[c + 2], sh[c + 2]), 0.f);
    v.w = fmaxf(fmaf(v.w, sc[c + 3], sh[c + 3]), 0.f);
    o4[i] = v;
  }
}

// ---------------------------------------------------------------------------
extern "C" void kernel_launch(void* const* d_in, const int* in_sizes, int n_in,
                              void* d_out, int out_size, void* d_ws, size_t ws_size,
                              hipStream_t stream) {
  const float* feats = (const float*)d_in[0];
  const float* W     = (const float*)d_in[1];
  const float* gamma = (const float*)d_in[2];
  const float* beta  = (const float*)d_in[3];
  const int*   gidx  = (const int*)d_in[4];
  float* out = (float*)d_out;

  float* ss = (float*)d_ws;                                     // 2 KB
  unsigned short* Wt = (unsigned short*)((char*)d_ws + 4096);   // 512 KB
  float* partial  = (float*)((char*)d_ws + 4096 + 524288);      // 3.2 MB
  float* partial2 = (float*)((char*)partial + (size_t)NBLK * 512 * 4);  // 128 KB
  size_t raw_off = 4096 + 524288 + (size_t)NBLK * 512 * 4 + 131072;
  raw_off = (raw_off + 255) & ~(size_t)255;
  const size_t RAW_BYTES = (size_t)MOUT * COUT * 2;
  bool bf16raw = ws_size >= raw_off + RAW_BYTES;
  unsigned short* raw = bf16raw ? (unsigned short*)((char*)d_ws + raw_off) : nullptr;

  hipLaunchKernelGGL(prep_kernel, dim3(16), dim3(256), 0, stream, W, Wt);
  hipLaunchKernelGGL(conv_kernel, dim3(NBLK), dim3(THREADS), 0, stream,
                     feats, Wt, gidx, raw, bf16raw ? nullptr : out, partial);
  hipLaunchKernelGGL(reduce_kernel, dim3(64), dim3(512), 0, stream,
                     partial, partial2);
  hipLaunchKernelGGL(finalize_kernel, dim3(1), dim3(256), 0, stream,
                     partial2, gamma, beta, ss);
  if (bf16raw)
    hipLaunchKernelGGL(apply_bf16, dim3(2048), dim3(256), 0, stream, raw, out, ss);
  else
    hipLaunchKernelGGL(apply_f32, dim3(2048), dim3(256), 0, stream, out, ss);
}